// Round 2
// 104.608 us; speedup vs baseline: 1.0012x; 1.0012x over previous
//
#include <hip/hip_runtime.h>

// VQ color lookup, round 12: R11 resubmit with the d_ws fault removed.
// R11 post-mortem: container died twice with no test output -> GPU memory
// fault, and the only new unguarded write was prep_kernel storing 8 KB into
// d_ws (size unknown, possibly 0/null). Fix: pack the pair table into a
// __device__ global (static 8 KB) instead of d_ws. Inter-kernel visibility
// is the standard dispatch release/acquire (same as loss memset in R1-R10).
// Perf design unchanged from R11:
//   R10 was VALU-bound (VALUBusy 72%, HBM 2%): 136 VALU-cyc/pair-iter
//   (28 v_pk @4cyc + 12 select @2cyc) x 512 iter/SIMD = ~29us floor,
//   measured 38us busy + 15us idle = per-iter ds_read lgkm bubbles at
//   ~3.3 waves/SIMD. Palette pair is wave-uniform -> fetch via
//   s_load_dwordx8 on the SMEM pipe (8 KB table, K$-resident). v_pk takes
//   one 64b scalar src: cx/cy/cz/cw are SGPR pairs (op_sel swapped into
//   src0; mul commutes -> bit-identical rounding to R10). Double-buffer
//   A/B; fences tied "+s" through the buffer (no hoist of extraction past
//   the wait); exactly one SMEM op outstanding per lgkmcnt(0) fence (SMEM
//   completion may be OOO; only 0 is safe). Removes stab LDS + staging +
//   first barrier + 2 ds_read/iter. Prep kernel also zeroes loss.
// Numerics: identical op sequence to R10 (halved distance, contract-off,
// left-assoc) -> expect absmax 0.0.

#define KPAL 512
#define HW   65536            // 256*256
#define CHW  (3 * HW)
#define NPIX (8 * HW)         // 524288 pixels
#define NELEM (NPIX * 3)      // 1572864 output color elements
#define PPT   4               // pixels per thread (64 lanes * 4 = 256 px/block)
#define NWAVE 4
#define PAIRS_PER_WAVE (KPAL / 2 / NWAVE)   // 64

typedef float f2  __attribute__((ext_vector_type(2)));
typedef float f8v __attribute__((ext_vector_type(8)));

struct __align__(32) Pair {   // palette entries 2j (lo half) and 2j+1 (hi)
    f2 x, y, z, w;            // w = 0.5 * ||t||^2 (contract-off, exact halve)
};

__device__ Pair g_pairs[KPAL / 2];          // 8 KB static device memory

// Pack the pair table; zero the loss accumulator.
__global__ void prep_kernel(const float* __restrict__ table,
                            float* __restrict__ loss)
{
    const int j = threadIdx.x;            // 0..255
    if (j == 0) *loss = 0.0f;
    const float a0 = table[6 * j + 0], a1 = table[6 * j + 1], a2 = table[6 * j + 2];
    const float b0 = table[6 * j + 3], b1 = table[6 * j + 4], b2 = table[6 * j + 5];
    float aw, bw;
    {
#pragma clang fp contract(off)
        aw = a0 * a0 + a1 * a1 + a2 * a2;
        bw = b0 * b0 + b1 * b1 + b2 * b2;
    }
    Pair p;
    p.x = (f2){a0, b0};
    p.y = (f2){a1, b1};
    p.z = (f2){a2, b2};
    p.w = (f2){0.5f * aw, 0.5f * bw};     // exact
    g_pairs[j] = p;
}

// 4 pixels x 1 palette pair; palette halves (cx,cy,cz,cw) are SGPR pairs.
// Same op order/rounding as R10: d = z0*cx; d += z1*cy; d += z2*cz;
// d = hz - d; d += ht2.  ZA=(z0,z1), ZB=(z2,hz); op_sel broadcasts the
// pixel component; exactly one scalar source per instruction.
static __device__ __forceinline__ void quad_dist_s(
    f2 cx, f2 cy, f2 cz, f2 cw,
    f2 A0, f2 B0, f2 A1, f2 B1, f2 A2, f2 B2, f2 A3, f2 B3,
    f2& r0, f2& r1, f2& r2, f2& r3)
{
    f2 d0, d1, d2, d3, t0, t1, t2, t3;
    asm("v_pk_mul_f32 %[d0], %[cx], %[A0] op_sel:[0,0] op_sel_hi:[1,0]\n\t"
        "v_pk_mul_f32 %[d1], %[cx], %[A1] op_sel:[0,0] op_sel_hi:[1,0]\n\t"
        "v_pk_mul_f32 %[d2], %[cx], %[A2] op_sel:[0,0] op_sel_hi:[1,0]\n\t"
        "v_pk_mul_f32 %[d3], %[cx], %[A3] op_sel:[0,0] op_sel_hi:[1,0]\n\t"
        "v_pk_mul_f32 %[t0], %[cy], %[A0] op_sel:[0,1] op_sel_hi:[1,1]\n\t"
        "v_pk_mul_f32 %[t1], %[cy], %[A1] op_sel:[0,1] op_sel_hi:[1,1]\n\t"
        "v_pk_mul_f32 %[t2], %[cy], %[A2] op_sel:[0,1] op_sel_hi:[1,1]\n\t"
        "v_pk_mul_f32 %[t3], %[cy], %[A3] op_sel:[0,1] op_sel_hi:[1,1]\n\t"
        "v_pk_add_f32 %[d0], %[d0], %[t0]\n\t"
        "v_pk_add_f32 %[d1], %[d1], %[t1]\n\t"
        "v_pk_add_f32 %[d2], %[d2], %[t2]\n\t"
        "v_pk_add_f32 %[d3], %[d3], %[t3]\n\t"
        "v_pk_mul_f32 %[t0], %[cz], %[B0] op_sel:[0,0] op_sel_hi:[1,0]\n\t"
        "v_pk_mul_f32 %[t1], %[cz], %[B1] op_sel:[0,0] op_sel_hi:[1,0]\n\t"
        "v_pk_mul_f32 %[t2], %[cz], %[B2] op_sel:[0,0] op_sel_hi:[1,0]\n\t"
        "v_pk_mul_f32 %[t3], %[cz], %[B3] op_sel:[0,0] op_sel_hi:[1,0]\n\t"
        "v_pk_add_f32 %[d0], %[d0], %[t0]\n\t"
        "v_pk_add_f32 %[d1], %[d1], %[t1]\n\t"
        "v_pk_add_f32 %[d2], %[d2], %[t2]\n\t"
        "v_pk_add_f32 %[d3], %[d3], %[t3]\n\t"
        "v_pk_add_f32 %[d0], %[B0], %[d0] op_sel:[1,0] op_sel_hi:[1,1] neg_lo:[0,1] neg_hi:[0,1]\n\t"
        "v_pk_add_f32 %[d1], %[B1], %[d1] op_sel:[1,0] op_sel_hi:[1,1] neg_lo:[0,1] neg_hi:[0,1]\n\t"
        "v_pk_add_f32 %[d2], %[B2], %[d2] op_sel:[1,0] op_sel_hi:[1,1] neg_lo:[0,1] neg_hi:[0,1]\n\t"
        "v_pk_add_f32 %[d3], %[B3], %[d3] op_sel:[1,0] op_sel_hi:[1,1] neg_lo:[0,1] neg_hi:[0,1]\n\t"
        "v_pk_add_f32 %[d0], %[d0], %[cw]\n\t"
        "v_pk_add_f32 %[d1], %[d1], %[cw]\n\t"
        "v_pk_add_f32 %[d2], %[d2], %[cw]\n\t"
        "v_pk_add_f32 %[d3], %[d3], %[cw]"
        : [d0] "=&v"(d0), [d1] "=&v"(d1), [d2] "=&v"(d2), [d3] "=&v"(d3),
          [t0] "=&v"(t0), [t1] "=&v"(t1), [t2] "=&v"(t2), [t3] "=&v"(t3)
        : [A0] "v"(A0), [B0] "v"(B0), [A1] "v"(A1), [B1] "v"(B1),
          [A2] "v"(A2), [B2] "v"(B2), [A3] "v"(A3), [B3] "v"(B3),
          [cx] "s"(cx), [cy] "s"(cy), [cz] "s"(cz), [cw] "s"(cw));
    r0 = d0; r1 = d1; r2 = d2; r3 = d3;
}

// Issue one s_load_dwordx8 (one Pair) into an SGPR octet; fence ties the
// wait through the destination so no consumer can be scheduled before it.
#define SLOAD(dst, off) \
    asm volatile("s_load_dwordx8 %0, %1, %2" : "=s"(dst) : "s"(pairs), "s"(off))
#define SFENCE(dst) \
    asm volatile("s_waitcnt lgkmcnt(0)" : "+s"(dst))

__global__ __launch_bounds__(256, 4)
void vq_kernel(const float* __restrict__ z,
               const float* __restrict__ table,
               float* __restrict__ out,
               float* __restrict__ loss)
{
    __shared__ float cb_best[NWAVE][256];   // 4 KB
    __shared__ int   cb_bi[NWAVE][256];     // 4 KB
    __shared__ float wsum[NWAVE];
    const Pair* pairs = g_pairs;
    const int t = threadIdx.x;
    const int w = t >> 6, lane = t & 63;
    const int wu = __builtin_amdgcn_readfirstlane(w);   // wave-uniform SGPR

    // Block covers 256 consecutive pixels; all 4 waves process the same px.
    const int blockbase = blockIdx.x * 256;
    const int b  = blockbase >> 16;           // blocks never straddle batch
    const int p0 = blockbase & (HW - 1);
    const int base0 = b * CHW + p0 + lane;    // pixel i at base0 + 64*i

    f2 ZA[PPT], ZB[PPT];                      // (z0,z1), (z2, 0.5*||z||^2)
#pragma unroll
    for (int i = 0; i < PPT; ++i) {
        const int base = base0 + 64 * i;
        const float z0 = z[base];
        const float z1 = z[base + HW];
        const float z2 = z[base + 2 * HW];
        float zs;
        {
#pragma clang fp contract(off)
            zs = z0 * z0 + z1 * z1 + z2 * z2;
        }
        ZA[i] = (f2){z0, z1};
        ZB[i] = (f2){z2, 0.5f * zs};          // exact halve
    }

    float best[PPT];
    int   bj[PPT];                            // global pair index
#pragma unroll
    for (int i = 0; i < PPT; ++i) { best[i] = 3.4e38f; bj[i] = wu * PAIRS_PER_WAVE; }

    // Wave w scans its palette quarter; pairs arrive via pipelined s_load.
    const unsigned wbase = (unsigned)(wu * PAIRS_PER_WAVE) * 32u;

#define PAIR_STEP(V, JG)                                                     \
    do {                                                                     \
        const f2 cx = (f2){(V)[0], (V)[1]};                                  \
        const f2 cy = (f2){(V)[2], (V)[3]};                                  \
        const f2 cz = (f2){(V)[4], (V)[5]};                                  \
        const f2 cw = (f2){(V)[6], (V)[7]};                                  \
        f2 r[PPT];                                                           \
        quad_dist_s(cx, cy, cz, cw,                                          \
                    ZA[0], ZB[0], ZA[1], ZB[1], ZA[2], ZB[2], ZA[3], ZB[3],  \
                    r[0], r[1], r[2], r[3]);                                 \
        const int jgv = (JG);                                                \
        _Pragma("unroll")                                                    \
        for (int i = 0; i < PPT; ++i) {                                      \
            const float mn = fminf(fminf(best[i], r[i].x), r[i].y);          \
            const bool imp = mn < best[i];                                   \
            bj[i] = imp ? jgv : bj[i];                                       \
            best[i] = mn;                                                    \
        }                                                                    \
    } while (0)

    {
        f8v A, B;
        SLOAD(A, wbase);
        for (int c = 0; c < PAIRS_PER_WAVE; c += 2) {
            SFENCE(A);                                    // only A outstanding
            const unsigned offB = wbase + (unsigned)(c + 1) * 32u;
            SLOAD(B, offB);                               // hides under compute(A)
            PAIR_STEP(A, wu * PAIRS_PER_WAVE + c);
            SFENCE(B);                                    // only B outstanding
            if (c + 2 < PAIRS_PER_WAVE) {
                const unsigned offA = wbase + (unsigned)(c + 2) * 32u;
                SLOAD(A, offA);                           // hides under compute(B)
            }
            PAIR_STEP(B, wu * PAIRS_PER_WAVE + c + 1);
        }
    }
#undef PAIR_STEP

    // Resolve lo/hi within the winning pair (exact lo recompute), publish.
#pragma unroll
    for (int i = 0; i < PPT; ++i) {
        const Pair cc = pairs[bj[i]];         // per-lane gather, L1-hit (8 KB)
        float dx;
        {
#pragma clang fp contract(off)
            float m = ZA[i].x * cc.x.x;       // z0*cx
            m = m + ZA[i].y * cc.y.x;         // + z1*cy
            m = m + ZB[i].x * cc.z.x;         // + z2*cz
            float s = ZB[i].y - m;            // hz - cross
            dx = s + cc.w.x;                  // + ht2
        }
        const int bi = (dx == best[i]) ? 2 * bj[i] : 2 * bj[i] + 1;
        cb_best[w][lane + 64 * i] = best[i];
        cb_bi[w][lane + 64 * i]   = bi;
    }
    __syncthreads();

    // Combine quarters (ordered strict < => numpy first-index), write, loss.
    // px p = t was scanned by THIS thread at slot i == w: reuse regs, no z re-read.
    f2 zA = ZA[0], zB = ZB[0];
    if (w == 1)      { zA = ZA[1]; zB = ZB[1]; }
    else if (w == 2) { zA = ZA[2]; zB = ZB[2]; }
    else if (w == 3) { zA = ZA[3]; zB = ZB[3]; }

    float lsum = 0.0f;
    {
        const int p = t;                      // 0..255 within block
        float bb = cb_best[0][p];
        int   kk = cb_bi[0][p];
#pragma unroll
        for (int ww = 1; ww < NWAVE; ++ww) {
            const float d  = cb_best[ww][p];
            const int   k2 = cb_bi[ww][p];
            if (d < bb) { bb = d; kk = k2; }
        }
        const int base = b * CHW + p0 + p;
        const float c0 = table[3 * kk + 0];
        const float c1 = table[3 * kk + 1];
        const float c2 = table[3 * kk + 2];
        out[base]          = c0;
        out[base + HW]     = c1;
        out[base + 2 * HW] = c2;
        const float e0 = c0 - zA.x, e1 = c1 - zA.y, e2 = c2 - zB.x;
        lsum = e0 * e0 + e1 * e1 + e2 * e2;
    }

    for (int off = 32; off > 0; off >>= 1)
        lsum += __shfl_down(lsum, off);

    if ((t & 63) == 0) wsum[w] = lsum;
    __syncthreads();
    if (t == 0) {
        const float s = wsum[0] + wsum[1] + wsum[2] + wsum[3];
        atomicAdd(loss, s * (11.0f / (float)NELEM));
    }
}

extern "C" void kernel_launch(void* const* d_in, const int* in_sizes, int n_in,
                              void* d_out, int out_size, void* d_ws, size_t ws_size,
                              hipStream_t stream)
{
    const float* z     = (const float*)d_in[0];
    const float* table = (const float*)d_in[1];
    float* out  = (float*)d_out;
    float* loss = out + NELEM;

    prep_kernel<<<1, 256, 0, stream>>>(table, loss);
    vq_kernel<<<NPIX / 256, 256, 0, stream>>>(z, table, out, loss);
}

// Round 3
// 95.518 us; speedup vs baseline: 1.0964x; 1.0952x over previous
//
#include <hip/hip_runtime.h>

// VQ color lookup, round 13: cut VALU work with v_pk_fma_f32.
// R12 post-mortem: SMEM palette path == R10 LDS path (54.0 vs 52.9 us,
// VALUBusy ~70% both) -> palette delivery was never the bottleneck; the
// kernel is VALU-work-bound. Fix: fuse the cross-product chain. Palette is
// stored NEGATED (n = -t) so score = fma(nz,z2, fma(ny,z1, fma(nx,z0,hz)))
// + ht2 == hz - z.t + 0.5||t||^2. hz rides in ZB.hi and is broadcast into
// the fma src2 via op_sel (no extra reg, and each instr reads exactly ONE
// sgpr operand -> constant-bus legal). Per pair per px: 7 pk-ops -> 4.
// Inner step 136 -> 88 VALU-cyc; floor 29 -> 18.8 us.
// Numerics: fma perturbs scores ~1 ulp. The halved/re-associated score of
// R1-R12 already differed from the JAX (XLA, fma-fused) reference by the
// same scale and absmax stayed 0.0 on this fixed seed-0 dataset -> argmin
// gaps >> ulp noise. Resolve replicates the pk lo-half bitwise via scalar
// fmaf, so best/resolve/combine stay self-consistent.
// SMEM: s_load_dwordx16 (2 Pairs / 64 B), A/B double-buffer, one fence per
// 2 pair-steps (~176 cyc cover), exactly one SMEM op outstanding per
// lgkmcnt(0) fence, fence tied "+s" through the buffer.

#define KPAL 512
#define HW   65536            // 256*256
#define CHW  (3 * HW)
#define NPIX (8 * HW)         // 524288 pixels
#define NELEM (NPIX * 3)      // 1572864 output color elements
#define PPT   4               // pixels per thread (64 lanes * 4 = 256 px/block)
#define NWAVE 4
#define PAIRS_PER_WAVE (KPAL / 2 / NWAVE)   // 64

typedef float f2   __attribute__((ext_vector_type(2)));
typedef float f16v __attribute__((ext_vector_type(16)));

struct __align__(32) Pair {   // palette entries 2j (lo half) and 2j+1 (hi)
    f2 x, y, z, w;            // x,y,z = NEGATED color; w = 0.5 * ||t||^2
};

__device__ Pair g_pairs[KPAL / 2];          // 8 KB static device memory

// Pack the negated pair table; zero the loss accumulator.
__global__ void prep_kernel(const float* __restrict__ table,
                            float* __restrict__ loss)
{
    const int j = threadIdx.x;            // 0..255
    if (j == 0) *loss = 0.0f;
    const float a0 = table[6 * j + 0], a1 = table[6 * j + 1], a2 = table[6 * j + 2];
    const float b0 = table[6 * j + 3], b1 = table[6 * j + 4], b2 = table[6 * j + 5];
    float aw, bw;
    {
#pragma clang fp contract(off)
        aw = a0 * a0 + a1 * a1 + a2 * a2;
        bw = b0 * b0 + b1 * b1 + b2 * b2;
    }
    Pair p;
    p.x = (f2){-a0, -b0};
    p.y = (f2){-a1, -b1};
    p.z = (f2){-a2, -b2};
    p.w = (f2){0.5f * aw, 0.5f * bw};     // exact
    g_pairs[j] = p;
}

// 4 pixels x 1 palette pair; negated palette halves (nx,ny,nz,cw) are SGPR
// pairs. Score lo-half: fma(nx.lo, z0, hz); fma(ny.lo, z1, .); fma(nz.lo,
// z2, .); + cw.lo.  ZA=(z0,z1), ZB=(z2,hz); op_sel broadcasts the pixel
// component (and hz from ZB.hi); exactly one scalar source per instruction.
static __device__ __forceinline__ void quad_dist_s(
    f2 nx, f2 ny, f2 nz, f2 cw,
    f2 A0, f2 B0, f2 A1, f2 B1, f2 A2, f2 B2, f2 A3, f2 B3,
    f2& r0, f2& r1, f2& r2, f2& r3)
{
    f2 d0, d1, d2, d3;
    asm("v_pk_fma_f32 %[d0], %[nx], %[A0], %[B0] op_sel:[0,0,1] op_sel_hi:[1,0,1]\n\t"
        "v_pk_fma_f32 %[d1], %[nx], %[A1], %[B1] op_sel:[0,0,1] op_sel_hi:[1,0,1]\n\t"
        "v_pk_fma_f32 %[d2], %[nx], %[A2], %[B2] op_sel:[0,0,1] op_sel_hi:[1,0,1]\n\t"
        "v_pk_fma_f32 %[d3], %[nx], %[A3], %[B3] op_sel:[0,0,1] op_sel_hi:[1,0,1]\n\t"
        "v_pk_fma_f32 %[d0], %[ny], %[A0], %[d0] op_sel:[0,1,0] op_sel_hi:[1,1,1]\n\t"
        "v_pk_fma_f32 %[d1], %[ny], %[A1], %[d1] op_sel:[0,1,0] op_sel_hi:[1,1,1]\n\t"
        "v_pk_fma_f32 %[d2], %[ny], %[A2], %[d2] op_sel:[0,1,0] op_sel_hi:[1,1,1]\n\t"
        "v_pk_fma_f32 %[d3], %[ny], %[A3], %[d3] op_sel:[0,1,0] op_sel_hi:[1,1,1]\n\t"
        "v_pk_fma_f32 %[d0], %[nz], %[B0], %[d0] op_sel:[0,0,0] op_sel_hi:[1,0,1]\n\t"
        "v_pk_fma_f32 %[d1], %[nz], %[B1], %[d1] op_sel:[0,0,0] op_sel_hi:[1,0,1]\n\t"
        "v_pk_fma_f32 %[d2], %[nz], %[B2], %[d2] op_sel:[0,0,0] op_sel_hi:[1,0,1]\n\t"
        "v_pk_fma_f32 %[d3], %[nz], %[B3], %[d3] op_sel:[0,0,0] op_sel_hi:[1,0,1]\n\t"
        "v_pk_add_f32 %[d0], %[d0], %[cw]\n\t"
        "v_pk_add_f32 %[d1], %[d1], %[cw]\n\t"
        "v_pk_add_f32 %[d2], %[d2], %[cw]\n\t"
        "v_pk_add_f32 %[d3], %[d3], %[cw]"
        : [d0] "=&v"(d0), [d1] "=&v"(d1), [d2] "=&v"(d2), [d3] "=&v"(d3)
        : [A0] "v"(A0), [B0] "v"(B0), [A1] "v"(A1), [B1] "v"(B1),
          [A2] "v"(A2), [B2] "v"(B2), [A3] "v"(A3), [B3] "v"(B3),
          [nx] "s"(nx), [ny] "s"(ny), [nz] "s"(nz), [cw] "s"(cw));
    r0 = d0; r1 = d1; r2 = d2; r3 = d3;
}

// One s_load_dwordx16 (two Pairs) into an SGPR 16-tuple; fence ties the
// wait through the destination so no consumer can be scheduled before it.
#define SLOAD2(dst, off) \
    asm volatile("s_load_dwordx16 %0, %1, %2" : "=s"(dst) : "s"(pairs), "s"(off))
#define SFENCE(dst) \
    asm volatile("s_waitcnt lgkmcnt(0)" : "+s"(dst))

__global__ __launch_bounds__(256, 4)
void vq_kernel(const float* __restrict__ z,
               const float* __restrict__ table,
               float* __restrict__ out,
               float* __restrict__ loss)
{
    __shared__ float cb_best[NWAVE][256];   // 4 KB
    __shared__ int   cb_bi[NWAVE][256];     // 4 KB
    __shared__ float wsum[NWAVE];
    const Pair* pairs = g_pairs;
    const int t = threadIdx.x;
    const int w = t >> 6, lane = t & 63;
    const int wu = __builtin_amdgcn_readfirstlane(w);   // wave-uniform SGPR

    // Block covers 256 consecutive pixels; all 4 waves process the same px.
    const int blockbase = blockIdx.x * 256;
    const int b  = blockbase >> 16;           // blocks never straddle batch
    const int p0 = blockbase & (HW - 1);
    const int base0 = b * CHW + p0 + lane;    // pixel i at base0 + 64*i

    f2 ZA[PPT], ZB[PPT];                      // (z0,z1), (z2, 0.5*||z||^2)
#pragma unroll
    for (int i = 0; i < PPT; ++i) {
        const int base = base0 + 64 * i;
        const float z0 = z[base];
        const float z1 = z[base + HW];
        const float z2 = z[base + 2 * HW];
        float zs;
        {
#pragma clang fp contract(off)
            zs = z0 * z0 + z1 * z1 + z2 * z2;
        }
        ZA[i] = (f2){z0, z1};
        ZB[i] = (f2){z2, 0.5f * zs};          // exact halve
    }

    float best[PPT];
    int   bj[PPT];                            // global pair index
#pragma unroll
    for (int i = 0; i < PPT; ++i) { best[i] = 3.4e38f; bj[i] = wu * PAIRS_PER_WAVE; }

    // Wave w scans its palette quarter; 2 pairs per pipelined s_load.
    const unsigned wbase = (unsigned)(wu * PAIRS_PER_WAVE) * 32u;

#define PAIR_STEP(V, H, JG)                                                  \
    do {                                                                     \
        const f2 nx = (f2){(V)[(H) + 0], (V)[(H) + 1]};                      \
        const f2 ny = (f2){(V)[(H) + 2], (V)[(H) + 3]};                      \
        const f2 nz = (f2){(V)[(H) + 4], (V)[(H) + 5]};                      \
        const f2 cw = (f2){(V)[(H) + 6], (V)[(H) + 7]};                      \
        f2 r[PPT];                                                           \
        quad_dist_s(nx, ny, nz, cw,                                          \
                    ZA[0], ZB[0], ZA[1], ZB[1], ZA[2], ZB[2], ZA[3], ZB[3],  \
                    r[0], r[1], r[2], r[3]);                                 \
        const int jgv = (JG);                                                \
        _Pragma("unroll")                                                    \
        for (int i = 0; i < PPT; ++i) {                                      \
            const float mn = fminf(fminf(best[i], r[i].x), r[i].y);          \
            const bool imp = mn < best[i];                                   \
            bj[i] = imp ? jgv : bj[i];                                       \
            best[i] = mn;                                                    \
        }                                                                    \
    } while (0)

    {
        f16v A, B;
        SLOAD2(A, wbase);                                 // pairs 0,1
#pragma unroll 1
        for (int c = 0; c < PAIRS_PER_WAVE; c += 4) {
            SFENCE(A);                                    // only A outstanding
            const unsigned offB = wbase + (unsigned)(c + 2) * 32u;
            SLOAD2(B, offB);                              // hides under 2 steps
            PAIR_STEP(A, 0, wu * PAIRS_PER_WAVE + c);
            PAIR_STEP(A, 8, wu * PAIRS_PER_WAVE + c + 1);
            SFENCE(B);                                    // only B outstanding
            if (c + 4 < PAIRS_PER_WAVE) {
                const unsigned offA = wbase + (unsigned)(c + 4) * 32u;
                SLOAD2(A, offA);                          // hides under 2 steps
            }
            PAIR_STEP(B, 0, wu * PAIRS_PER_WAVE + c + 2);
            PAIR_STEP(B, 8, wu * PAIRS_PER_WAVE + c + 3);
        }
    }
#undef PAIR_STEP

    // Resolve lo/hi within the winning pair (bitwise pk-lo recompute), publish.
#pragma unroll
    for (int i = 0; i < PPT; ++i) {
        const Pair cc = pairs[bj[i]];         // per-lane gather, L1-hit (8 KB)
        float m = fmaf(cc.x.x, ZA[i].x, ZB[i].y);   // nx*z0 + hz
        m = fmaf(cc.y.x, ZA[i].y, m);               // + ny*z1
        m = fmaf(cc.z.x, ZB[i].x, m);               // + nz*z2
        const float dx = m + cc.w.x;                // + ht2
        const int bi = (dx == best[i]) ? 2 * bj[i] : 2 * bj[i] + 1;
        cb_best[w][lane + 64 * i] = best[i];
        cb_bi[w][lane + 64 * i]   = bi;
    }
    __syncthreads();

    // Combine quarters (ordered strict < => first-index tiebreak), write, loss.
    // px p = t was scanned by THIS thread at slot i == w: reuse regs, no z re-read.
    f2 zA = ZA[0], zB = ZB[0];
    if (w == 1)      { zA = ZA[1]; zB = ZB[1]; }
    else if (w == 2) { zA = ZA[2]; zB = ZB[2]; }
    else if (w == 3) { zA = ZA[3]; zB = ZB[3]; }

    float lsum = 0.0f;
    {
        const int p = t;                      // 0..255 within block
        float bb = cb_best[0][p];
        int   kk = cb_bi[0][p];
#pragma unroll
        for (int ww = 1; ww < NWAVE; ++ww) {
            const float d  = cb_best[ww][p];
            const int   k2 = cb_bi[ww][p];
            if (d < bb) { bb = d; kk = k2; }
        }
        const int base = b * CHW + p0 + p;
        const float c0 = table[3 * kk + 0];
        const float c1 = table[3 * kk + 1];
        const float c2 = table[3 * kk + 2];
        out[base]          = c0;
        out[base + HW]     = c1;
        out[base + 2 * HW] = c2;
        const float e0 = c0 - zA.x, e1 = c1 - zA.y, e2 = c2 - zB.x;
        lsum = e0 * e0 + e1 * e1 + e2 * e2;
    }

    for (int off = 32; off > 0; off >>= 1)
        lsum += __shfl_down(lsum, off);

    if ((t & 63) == 0) wsum[w] = lsum;
    __syncthreads();
    if (t == 0) {
        const float s = wsum[0] + wsum[1] + wsum[2] + wsum[3];
        atomicAdd(loss, s * (11.0f / (float)NELEM));
    }
}

extern "C" void kernel_launch(void* const* d_in, const int* in_sizes, int n_in,
                              void* d_out, int out_size, void* d_ws, size_t ws_size,
                              hipStream_t stream)
{
    const float* z     = (const float*)d_in[0];
    const float* table = (const float*)d_in[1];
    float* out  = (float*)d_out;
    float* loss = out + NELEM;

    prep_kernel<<<1, 256, 0, stream>>>(table, loss);
    vq_kernel<<<NPIX / 256, 256, 0, stream>>>(z, table, out, loss);
}